// Round 8
// baseline (623.717 us; speedup 1.0000x reference)
//
#include <hip/hip_runtime.h>
#include <stdint.h>

#define HH 2048
#define BB 16384
#define NK (HH / 64)        // 32 K-steps of 64 bytes
#define NBH16 (1 << 21)     // (BB*HH)/16
#define NW16  (1 << 18)     // (HH*HH)/16

typedef int v4i __attribute__((ext_vector_type(4)));

__device__ __forceinline__ int clip127(int v){
  v = v > 127 ? 127 : v;
  return v < -127 ? -127 : v;
}
// floor division by 720 (matches Python //)
__device__ __forceinline__ int fdiv720(int r){
  int q = r / 720;
  return q - ((r - q * 720) < 0 ? 1 : 0);
}

__device__ __forceinline__ void pack16(const int* __restrict__ src, int8_t* __restrict__ dst, int i){
  const int4* s = (const int4*)src + (size_t)i * 4;
  int4 a = s[0], b = s[1], c = s[2], d = s[3];
  int4 o;
  o.x = (a.x & 255) | ((a.y & 255) << 8) | ((a.z & 255) << 16) | (a.w << 24);
  o.y = (b.x & 255) | ((b.y & 255) << 8) | ((b.z & 255) << 16) | (b.w << 24);
  o.z = (c.x & 255) | ((c.y & 255) << 8) | ((c.z & 255) << 16) | (c.w << 24);
  o.w = (d.x & 255) | ((d.y & 255) << 8) | ((d.z & 255) << 16) | (d.w << 24);
  ((int4*)dst)[i] = o;
}

// All six int32->int8 packs in one dispatch (region-decoded grid-stride).
__global__ void pack_all(const int* __restrict__ x,  const int* __restrict__ st,
                         const int* __restrict__ Wf, const int* __restrict__ Uf,
                         const int* __restrict__ Wh, const int* __restrict__ Uh,
                         int8_t* x8, int8_t* s8, int8_t* wf8, int8_t* uf8,
                         int8_t* wh8, int8_t* uh8){
  const int total = 2 * NBH16 + 4 * NW16;
  const int stride = gridDim.x * blockDim.x;
  for (int u = blockIdx.x * blockDim.x + threadIdx.x; u < total; u += stride){
    if (u < NBH16)            pack16(x,  x8,  u);
    else if (u < 2 * NBH16)   pack16(st, s8,  u - NBH16);
    else {
      const int v = u - 2 * NBH16;
      const int w = v >> 18;          // v / NW16
      const int i = v & (NW16 - 1);
      if      (w == 0) pack16(Wf, wf8, i);
      else if (w == 1) pack16(Uf, uf8, i);
      else if (w == 2) pack16(Wh, wh8, i);
      else             pack16(Uh, uh8, i);
    }
  }
}

// Duplicate first half of d_out into second half (int4). Fallback path only.
__global__ void dup_out(const int* __restrict__ src, int* __restrict__ dst, int n4){
  int stride = gridDim.x * blockDim.x;
  for (int i = blockIdx.x * blockDim.x + threadIdx.x; i < n4; i += stride)
    ((int4*)dst)[i] = ((const int4*)src)[i];
}

// Dual-GEMM 128x128 tile, 4 waves of 64x64 (LDS-read-minimal layout),
// double-buffered LDS (2x32KB) with TRUE counted-vmcnt pipeline:
// prologue stages tiles 0,1; loop waits vmcnt(8) (cur tile landed, next
// stays in flight), computes, barriers, stages tile k+2 into freed buffer.
// vmcnt never drains to 0 in the main loop (T4).
// Column-ownership XCD swizzle: XCD x owns col-tiles {2x,2x+1} -> per-XCD
// weight working set 1MB = L2-resident.
// PHASE 1: f_t = clip(clip(acc1//720)+clip(acc2//720)+bias); fg = f_t+127
//          fbuf[idx] = fg (int32); g8out[idx] = clip((fg*state)>>8)
// PHASE 2: h = clip(...); ns = clip(st + ((fbuf[idx]*(h-st))>>8));
//          fbuf[idx] = ns; if(out2) out2[idx] = ns
template<int PHASE>
__global__ __launch_bounds__(256, 2)
void gemm_dual(const int8_t* __restrict__ A1, const int8_t* __restrict__ A2,
               const int8_t* __restrict__ B1, const int8_t* __restrict__ B2,
               const int* __restrict__ bias,
               const int8_t* __restrict__ state8,
               int* fbuf, int8_t* __restrict__ g8out, int* __restrict__ out2)
{
  __shared__ __align__(16) int8_t lds[2 * 32768];   // dbuf x (A1,A2,B1,B2 x 8KB)
  const int tid  = threadIdx.x;
  const int lane = tid & 63;
  const int wave = tid >> 6;
  const int wrow = wave >> 1, wcol = wave & 1;

  // col-ownership XCD swizzle (assumes bid%8 round-robins XCDs; bijective)
  const int bid = blockIdx.x;
  const int j   = bid >> 3;
  const int rowbase = (j >> 1) * 128;                 // 0..127 row tiles
  const int colbase = ((bid & 7) * 2 + (j & 1)) * 128; // 0..15 col tiles

  v4i accA[4][4], accB[4][4];
  const v4i vzero = {0, 0, 0, 0};
#pragma unroll
  for (int m = 0; m < 4; m++)
#pragma unroll
    for (int n = 0; n < 4; n++){ accA[m][n] = vzero; accB[m][n] = vzero; }

  const int srow   = tid >> 2;   // 0..63 staging row
  const int schunk = tid & 3;    // 16B chunk within 64B row
  const int chunk  = lane >> 4;  // frag-read 16B chunk
  const int rl     = lane & 15;

  // stage K-slice kk of all 4 tiles into buffer buf: 8 loads per thread/wave
  auto STAGE = [&](int buf, int kk){
    const int k0 = kk * 64;
    const int bb = buf * 32768;
#pragma unroll
    for (int p = 0; p < 2; p++){
      const int row = p * 64 + srow;
      const int swc = schunk ^ ((row >> 1) & 3);   // inverse swizzle on source
      const size_t aoff = (size_t)(rowbase + row) * HH + k0 + swc * 16;
      const size_t boff = (size_t)(colbase + row) * HH + k0 + swc * 16;
      const int ldst = bb + p * 4096 + tid * 16;
      __builtin_amdgcn_global_load_lds((const __attribute__((address_space(1))) void*)(A1 + aoff),
                                       (__attribute__((address_space(3))) void*)(lds + ldst), 16, 0, 0);
      __builtin_amdgcn_global_load_lds((const __attribute__((address_space(1))) void*)(A2 + aoff),
                                       (__attribute__((address_space(3))) void*)(lds + 8192 + ldst), 16, 0, 0);
      __builtin_amdgcn_global_load_lds((const __attribute__((address_space(1))) void*)(B1 + boff),
                                       (__attribute__((address_space(3))) void*)(lds + 16384 + ldst), 16, 0, 0);
      __builtin_amdgcn_global_load_lds((const __attribute__((address_space(1))) void*)(B2 + boff),
                                       (__attribute__((address_space(3))) void*)(lds + 24576 + ldst), 16, 0, 0);
    }
  };

  auto COMPUTE = [&](int cb){
    // pair 1: A1 x B1
    {
      v4i af[4], bf[4];
#pragma unroll
      for (int m = 0; m < 4; m++){
        const int row = wrow * 64 + m * 16 + rl;
        af[m] = *(const v4i*)(lds + cb + row * 64 + ((chunk ^ ((row >> 1) & 3)) << 4));
      }
#pragma unroll
      for (int n = 0; n < 4; n++){
        const int row = wcol * 64 + n * 16 + rl;
        bf[n] = *(const v4i*)(lds + cb + 16384 + row * 64 + ((chunk ^ ((row >> 1) & 3)) << 4));
      }
#pragma unroll
      for (int m = 0; m < 4; m++)
#pragma unroll
        for (int n = 0; n < 4; n++)
          accA[m][n] = __builtin_amdgcn_mfma_i32_16x16x64_i8(af[m], bf[n], accA[m][n], 0, 0, 0);
    }
    // pair 2: A2 x B2
    {
      v4i af[4], bf[4];
#pragma unroll
      for (int m = 0; m < 4; m++){
        const int row = wrow * 64 + m * 16 + rl;
        af[m] = *(const v4i*)(lds + cb + 8192 + row * 64 + ((chunk ^ ((row >> 1) & 3)) << 4));
      }
#pragma unroll
      for (int n = 0; n < 4; n++){
        const int row = wcol * 64 + n * 16 + rl;
        bf[n] = *(const v4i*)(lds + cb + 24576 + row * 64 + ((chunk ^ ((row >> 1) & 3)) << 4));
      }
#pragma unroll
      for (int m = 0; m < 4; m++)
#pragma unroll
        for (int n = 0; n < 4; n++)
          accB[m][n] = __builtin_amdgcn_mfma_i32_16x16x64_i8(af[m], bf[n], accB[m][n], 0, 0, 0);
    }
  };

  // prologue: two tiles in flight (16 outstanding vmem ops per wave)
  STAGE(0, 0);
  STAGE(1, 1);

  for (int kk = 0; kk < NK - 1; ++kk){
    __builtin_amdgcn_sched_barrier(0);
    asm volatile("s_waitcnt vmcnt(8)" ::: "memory");   // tile kk landed; kk+1 in flight
    __builtin_amdgcn_s_barrier();                      // all waves' loads landed
    COMPUTE((kk & 1) * 32768);
    __builtin_amdgcn_sched_barrier(0);                 // reads pinned above barrier
    __builtin_amdgcn_s_barrier();                      // all waves done reading buf
    if (kk + 2 < NK) STAGE(kk & 1, kk + 2);            // refill freed buffer
  }
  __builtin_amdgcn_sched_barrier(0);
  asm volatile("s_waitcnt vmcnt(0)" ::: "memory");     // last tile landed
  __builtin_amdgcn_s_barrier();
  COMPUTE(((NK - 1) & 1) * 32768);

  // epilogue: C/D layout col=lane&15, row=(lane>>4)*4+reg
  const int q = lane >> 4;
#pragma unroll
  for (int m = 0; m < 4; m++){
#pragma unroll
    for (int n = 0; n < 4; n++){
      const int gcol = colbase + wcol * 64 + n * 16 + rl;
      const int bval = bias[gcol];
#pragma unroll
      for (int r = 0; r < 4; r++){
        const int grow = rowbase + wrow * 64 + m * 16 + q * 4 + r;
        const size_t idx = (size_t)grow * HH + gcol;
        const int v1 = clip127(fdiv720(accA[m][n][r]));
        const int v2 = clip127(fdiv720(accB[m][n][r]));
        const int t  = clip127(v1 + v2 + bval);   // f_t or h_tilde
        const int st = state8[idx];
        if (PHASE == 1){
          const int fg = t + 127;
          fbuf[idx]  = fg;                          // int32, d_out first half
          g8out[idx] = (int8_t)clip127((fg * st) >> 8);
        } else {
          const int fg = fbuf[idx];
          const int ns = clip127(st + ((fg * (t - st)) >> 8));
          fbuf[idx] = ns;                           // output 0 (same-thread r/w)
          if (out2) out2[idx] = ns;                 // output 1 (ws path)
        }
      }
    }
  }
}

extern "C" void kernel_launch(void* const* d_in, const int* in_sizes, int n_in,
                              void* d_out, int out_size, void* d_ws, size_t ws_size,
                              hipStream_t stream){
  const int* x  = (const int*)d_in[0];
  const int* st = (const int*)d_in[1];
  const int* Wf = (const int*)d_in[2];
  const int* Uf = (const int*)d_in[3];
  const int* bf = (const int*)d_in[4];
  const int* Wh = (const int*)d_in[5];
  const int* Uh = (const int*)d_in[6];
  const int* bh = (const int*)d_in[7];

  const size_t NBH = (size_t)BB * HH;   // 33,554,432 elements
  const size_t NW  = (size_t)HH * HH;   //  4,194,304 elements
  const size_t need = 3 * NBH + 4 * NW; // 112 MiB of int8 scratch

  // d_out: int32 x 2*NBH (tuple). First half carries fg (int32) then new_state.
  // Scratch (x8|s8|g8|4 weights) goes to d_ws if large enough; else to d_out's
  // second half (then dup_out fills output 1 at the end).
  int*    out1   = (int*)d_out;
  const bool wsp = (ws_size >= need);
  int8_t* base   = wsp ? (int8_t*)d_ws : (int8_t*)d_out + NBH * 4;
  int8_t* x8  = base;
  int8_t* s8  = x8 + NBH;
  int8_t* g8  = s8 + NBH;
  int8_t* wf8 = g8 + NBH;
  int8_t* uf8 = wf8 + NW;
  int8_t* wh8 = uf8 + NW;
  int8_t* uh8 = wh8 + NW;

  pack_all<<<2048, 256, 0, stream>>>(x, st, Wf, Uf, Wh, Uh,
                                     x8, s8, wf8, uf8, wh8, uh8);

  // grid: (16384/128) x (2048/128) = 2048 blocks of 256 threads
  gemm_dual<1><<<2048, 256, 0, stream>>>(x8, s8, wf8, uf8, bf, s8, out1, g8, nullptr);
  gemm_dual<2><<<2048, 256, 0, stream>>>(x8, g8, wh8, uh8, bh, s8, out1, nullptr,
                                         wsp ? out1 + NBH : nullptr);

  if (!wsp)
    dup_out<<<2048, 256, 0, stream>>>(out1, out1 + NBH, (int)(NBH / 4));
}

// Round 10
// 580.401 us; speedup vs baseline: 1.0746x; 1.0746x over previous
//
#include <hip/hip_runtime.h>
#include <stdint.h>

#define HH 2048
#define BB 16384
#define NK (HH / 64)        // 32 K-steps of 64 bytes
#define NBH16 (1 << 21)     // (BB*HH)/16
#define NW16  (1 << 18)     // (HH*HH)/16

typedef int v4i __attribute__((ext_vector_type(4)));

__device__ __forceinline__ int clip127(int v){
  v = v > 127 ? 127 : v;
  return v < -127 ? -127 : v;
}
// floor division by 720 (matches Python //)
__device__ __forceinline__ int fdiv720(int r){
  int q = r / 720;
  return q - ((r - q * 720) < 0 ? 1 : 0);
}

__device__ __forceinline__ void pack16(const int* __restrict__ src, int8_t* __restrict__ dst, int i){
  const int4* s = (const int4*)src + (size_t)i * 4;
  int4 a = s[0], b = s[1], c = s[2], d = s[3];
  int4 o;
  o.x = (a.x & 255) | ((a.y & 255) << 8) | ((a.z & 255) << 16) | (a.w << 24);
  o.y = (b.x & 255) | ((b.y & 255) << 8) | ((b.z & 255) << 16) | (b.w << 24);
  o.z = (c.x & 255) | ((c.y & 255) << 8) | ((c.z & 255) << 16) | (c.w << 24);
  o.w = (d.x & 255) | ((d.y & 255) << 8) | ((d.z & 255) << 16) | (d.w << 24);
  ((int4*)dst)[i] = o;
}

// All six int32->int8 packs in one dispatch (region-decoded grid-stride).
__global__ void pack_all(const int* __restrict__ x,  const int* __restrict__ st,
                         const int* __restrict__ Wf, const int* __restrict__ Uf,
                         const int* __restrict__ Wh, const int* __restrict__ Uh,
                         int8_t* x8, int8_t* s8, int8_t* wf8, int8_t* uf8,
                         int8_t* wh8, int8_t* uh8){
  const int total = 2 * NBH16 + 4 * NW16;
  const int stride = gridDim.x * blockDim.x;
  for (int u = blockIdx.x * blockDim.x + threadIdx.x; u < total; u += stride){
    if (u < NBH16)            pack16(x,  x8,  u);
    else if (u < 2 * NBH16)   pack16(st, s8,  u - NBH16);
    else {
      const int v = u - 2 * NBH16;
      const int w = v >> 18;          // v / NW16
      const int i = v & (NW16 - 1);
      if      (w == 0) pack16(Wf, wf8, i);
      else if (w == 1) pack16(Uf, uf8, i);
      else if (w == 2) pack16(Wh, wh8, i);
      else             pack16(Uh, uh8, i);
    }
  }
}

// Duplicate first half of d_out into second half (int4). Fallback path only.
__global__ void dup_out(const int* __restrict__ src, int* __restrict__ dst, int n4){
  int stride = gridDim.x * blockDim.x;
  for (int i = blockIdx.x * blockDim.x + threadIdx.x; i < n4; i += stride)
    ((int4*)dst)[i] = ((const int4*)src)[i];
}

// Dual-GEMM 128x128 tile — EXACT R3 main loop (proven 248us/dispatch):
// 4 waves of 64x64, single 32KB LDS buffer, serial STAGE->sync->COMPUTE->sync,
// natural block mapping (col-fast), XOR-swizzled LDS (0 bank conflicts).
// Epilogue variants (PHASE):
//  1: fg = clip(...)+127 -> fg8[idx] (u8); g8out[idx] = clip((fg*st)>>8)   [ws path]
//  2: h; ns = clip(st + ((fg8[idx]*(h-st))>>8)) -> out1[idx], out2[idx]    [ws path]
//  3: fg -> out1[idx] (int32 carrier); g8out = gated                       [fallback]
//  4: h; fg = out1[idx]; ns -> out1[idx] (same-thread r/w)                 [fallback]
template<int PHASE>
__global__ __launch_bounds__(256, 2)
void gemm_dual(const int8_t* __restrict__ A1, const int8_t* __restrict__ A2,
               const int8_t* __restrict__ B1, const int8_t* __restrict__ B2,
               const int* __restrict__ bias,
               const int8_t* __restrict__ state8,
               uint8_t* fg8, int8_t* __restrict__ g8out,
               int* __restrict__ out1, int* __restrict__ out2)
{
  __shared__ __align__(16) int8_t lds[4 * 8192];   // A1,A2,B1,B2 x 8KB
  const int tid  = threadIdx.x;
  const int lane = tid & 63;
  const int wave = tid >> 6;
  const int wrow = wave >> 1, wcol = wave & 1;
  const int bid  = blockIdx.x;
  const int rowbase = (bid >> 4) * 128;   // natural mapping (R3-proven)
  const int colbase = (bid & 15) * 128;

  v4i accA[4][4], accB[4][4];
  const v4i vzero = {0, 0, 0, 0};
#pragma unroll
  for (int m = 0; m < 4; m++)
#pragma unroll
    for (int n = 0; n < 4; n++){ accA[m][n] = vzero; accB[m][n] = vzero; }

  const int srow   = tid >> 2;   // 0..63 staging row within 64-row pass
  const int schunk = tid & 3;    // 16B chunk within 64B row
  const int chunk  = lane >> 4;  // frag-read 16B chunk
  const int rl     = lane & 15;

  for (int kk = 0; kk < NK; ++kk){
    const int k0 = kk * 64;
    // stage 4 tiles: linear LDS dest + inverse-swizzled global source
#pragma unroll
    for (int p = 0; p < 2; p++){
      const int row = p * 64 + srow;
      const int swc = schunk ^ ((row >> 1) & 3);       // XOR swizzle (involution)
      const size_t aoff = (size_t)(rowbase + row) * HH + k0 + swc * 16;
      const size_t boff = (size_t)(colbase + row) * HH + k0 + swc * 16;
      const int ldst = p * 4096 + tid * 16;
      __builtin_amdgcn_global_load_lds((const __attribute__((address_space(1))) void*)(A1 + aoff),
                                       (__attribute__((address_space(3))) void*)(lds + ldst), 16, 0, 0);
      __builtin_amdgcn_global_load_lds((const __attribute__((address_space(1))) void*)(A2 + aoff),
                                       (__attribute__((address_space(3))) void*)(lds + 8192 + ldst), 16, 0, 0);
      __builtin_amdgcn_global_load_lds((const __attribute__((address_space(1))) void*)(B1 + boff),
                                       (__attribute__((address_space(3))) void*)(lds + 16384 + ldst), 16, 0, 0);
      __builtin_amdgcn_global_load_lds((const __attribute__((address_space(1))) void*)(B2 + boff),
                                       (__attribute__((address_space(3))) void*)(lds + 24576 + ldst), 16, 0, 0);
    }
    __syncthreads();

    // pair 1: A1 x B1 -> accA
    {
      v4i af[4], bf[4];
#pragma unroll
      for (int m = 0; m < 4; m++){
        const int row = wrow * 64 + m * 16 + rl;
        af[m] = *(const v4i*)(lds + row * 64 + ((chunk ^ ((row >> 1) & 3)) << 4));
      }
#pragma unroll
      for (int n = 0; n < 4; n++){
        const int row = wcol * 64 + n * 16 + rl;
        bf[n] = *(const v4i*)(lds + 16384 + row * 64 + ((chunk ^ ((row >> 1) & 3)) << 4));
      }
#pragma unroll
      for (int m = 0; m < 4; m++)
#pragma unroll
        for (int n = 0; n < 4; n++)
          accA[m][n] = __builtin_amdgcn_mfma_i32_16x16x64_i8(af[m], bf[n], accA[m][n], 0, 0, 0);
    }
    // pair 2: A2 x B2 -> accB
    {
      v4i af[4], bf[4];
#pragma unroll
      for (int m = 0; m < 4; m++){
        const int row = wrow * 64 + m * 16 + rl;
        af[m] = *(const v4i*)(lds + 8192 + row * 64 + ((chunk ^ ((row >> 1) & 3)) << 4));
      }
#pragma unroll
      for (int n = 0; n < 4; n++){
        const int row = wcol * 64 + n * 16 + rl;
        bf[n] = *(const v4i*)(lds + 24576 + row * 64 + ((chunk ^ ((row >> 1) & 3)) << 4));
      }
#pragma unroll
      for (int m = 0; m < 4; m++)
#pragma unroll
        for (int n = 0; n < 4; n++)
          accB[m][n] = __builtin_amdgcn_mfma_i32_16x16x64_i8(af[m], bf[n], accB[m][n], 0, 0, 0);
    }
    __syncthreads();
  }

  // epilogue: C/D layout col=lane&15, row=(lane>>4)*4+reg
  const int q = lane >> 4;
#pragma unroll
  for (int m = 0; m < 4; m++){
#pragma unroll
    for (int n = 0; n < 4; n++){
      const int gcol = colbase + wcol * 64 + n * 16 + rl;
      const int bval = bias[gcol];
#pragma unroll
      for (int r = 0; r < 4; r++){
        const int grow = rowbase + wrow * 64 + m * 16 + q * 4 + r;
        const size_t idx = (size_t)grow * HH + gcol;
        const int v1 = clip127(fdiv720(accA[m][n][r]));
        const int v2 = clip127(fdiv720(accB[m][n][r]));
        const int t  = clip127(v1 + v2 + bval);   // f_t or h_tilde
        const int st = state8[idx];
        if (PHASE == 1){
          const int fg = t + 127;                   // in [0,254]
          fg8[idx]   = (uint8_t)fg;
          g8out[idx] = (int8_t)clip127((fg * st) >> 8);
        } else if (PHASE == 2){
          const int fg = (int)fg8[idx];
          const int ns = clip127(st + ((fg * (t - st)) >> 8));
          out1[idx] = ns;
          out2[idx] = ns;
        } else if (PHASE == 3){
          const int fg = t + 127;
          out1[idx]  = fg;                          // int32 fg carrier
          g8out[idx] = (int8_t)clip127((fg * st) >> 8);
        } else {   // PHASE 4
          const int fg = out1[idx];                 // int32 fg carrier
          const int ns = clip127(st + ((fg * (t - st)) >> 8));
          out1[idx] = ns;                           // same-thread r/w
        }
      }
    }
  }
}

extern "C" void kernel_launch(void* const* d_in, const int* in_sizes, int n_in,
                              void* d_out, int out_size, void* d_ws, size_t ws_size,
                              hipStream_t stream){
  const int* x  = (const int*)d_in[0];
  const int* st = (const int*)d_in[1];
  const int* Wf = (const int*)d_in[2];
  const int* Uf = (const int*)d_in[3];
  const int* bf = (const int*)d_in[4];
  const int* Wh = (const int*)d_in[5];
  const int* Uh = (const int*)d_in[6];
  const int* bh = (const int*)d_in[7];

  const size_t NBH = (size_t)BB * HH;   // 33,554,432 elements
  const size_t NW  = (size_t)HH * HH;   //  4,194,304 elements
  const size_t need = 4 * NBH + 4 * NW; // 144 MiB int8 scratch for ws path

  int* out1 = (int*)d_out;

  if (ws_size >= need){
    // ws path: x8 | s8 | g8 | fg8 | 4 weights in d_ws (144 MiB).
    int8_t*  x8  = (int8_t*)d_ws;
    int8_t*  s8  = x8 + NBH;
    int8_t*  g8  = s8 + NBH;
    uint8_t* fg8 = (uint8_t*)(g8 + NBH);
    int8_t*  wf8 = (int8_t*)fg8 + NBH;
    int8_t*  uf8 = wf8 + NW;
    int8_t*  wh8 = uf8 + NW;
    int8_t*  uh8 = wh8 + NW;
    pack_all<<<2048, 256, 0, stream>>>(x, st, Wf, Uf, Wh, Uh,
                                       x8, s8, wf8, uf8, wh8, uh8);
    gemm_dual<1><<<2048, 256, 0, stream>>>(x8, s8, wf8, uf8, bf, s8,
                                           fg8, g8, nullptr, nullptr);
    gemm_dual<2><<<2048, 256, 0, stream>>>(x8, g8, wh8, uh8, bh, s8,
                                           fg8, nullptr, out1, out1 + NBH);
  } else {
    // Fallback (R3-equivalent, known-correct): scratch x8|s8|g8|weights in
    // d_out's second half (112 MiB), fg carried as int32 in out1, dup at end.
    int8_t* base = (int8_t*)d_out + NBH * 4;
    int8_t* x8  = base;
    int8_t* s8  = x8 + NBH;
    int8_t* g8  = s8 + NBH;
    int8_t* wf8 = g8 + NBH;
    int8_t* uf8 = wf8 + NW;
    int8_t* wh8 = uf8 + NW;
    int8_t* uh8 = wh8 + NW;
    pack_all<<<2048, 256, 0, stream>>>(x, st, Wf, Uf, Wh, Uh,
                                       x8, s8, wf8, uf8, wh8, uh8);
    gemm_dual<3><<<2048, 256, 0, stream>>>(x8, s8, wf8, uf8, bf, s8,
                                           nullptr, g8, out1, nullptr);
    gemm_dual<4><<<2048, 256, 0, stream>>>(x8, g8, wh8, uh8, bh, s8,
                                           nullptr, nullptr, out1, nullptr);
    dup_out<<<2048, 256, 0, stream>>>(out1, out1 + NBH, (int)(NBH / 4));
  }
}

// Round 11
// 579.599 us; speedup vs baseline: 1.0761x; 1.0014x over previous
//
#include <hip/hip_runtime.h>
#include <stdint.h>

#define HH 2048
#define BB 16384
#define NK (HH / 64)        // 32 K-steps of 64 bytes
#define NBH16 (1 << 21)     // (BB*HH)/16
#define NW16  (1 << 18)     // (HH*HH)/16

typedef int v4i __attribute__((ext_vector_type(4)));

__device__ __forceinline__ int clip127(int v){
  v = v > 127 ? 127 : v;
  return v < -127 ? -127 : v;
}
// floor division by 720 (matches Python //)
__device__ __forceinline__ int fdiv720(int r){
  int q = r / 720;
  return q - ((r - q * 720) < 0 ? 1 : 0);
}

__device__ __forceinline__ void pack16(const int* __restrict__ src, int8_t* __restrict__ dst, int i){
  const int4* s = (const int4*)src + (size_t)i * 4;
  int4 a = s[0], b = s[1], c = s[2], d = s[3];
  int4 o;
  o.x = (a.x & 255) | ((a.y & 255) << 8) | ((a.z & 255) << 16) | (a.w << 24);
  o.y = (b.x & 255) | ((b.y & 255) << 8) | ((b.z & 255) << 16) | (b.w << 24);
  o.z = (c.x & 255) | ((c.y & 255) << 8) | ((c.z & 255) << 16) | (c.w << 24);
  o.w = (d.x & 255) | ((d.y & 255) << 8) | ((d.z & 255) << 16) | (d.w << 24);
  ((int4*)dst)[i] = o;
}

// All six int32->int8 packs in one dispatch (region-decoded grid-stride).
__global__ void pack_all(const int* __restrict__ x,  const int* __restrict__ st,
                         const int* __restrict__ Wf, const int* __restrict__ Uf,
                         const int* __restrict__ Wh, const int* __restrict__ Uh,
                         int8_t* x8, int8_t* s8, int8_t* wf8, int8_t* uf8,
                         int8_t* wh8, int8_t* uh8){
  const int total = 2 * NBH16 + 4 * NW16;
  const int stride = gridDim.x * blockDim.x;
  for (int u = blockIdx.x * blockDim.x + threadIdx.x; u < total; u += stride){
    if (u < NBH16)            pack16(x,  x8,  u);
    else if (u < 2 * NBH16)   pack16(st, s8,  u - NBH16);
    else {
      const int v = u - 2 * NBH16;
      const int w = v >> 18;          // v / NW16
      const int i = v & (NW16 - 1);
      if      (w == 0) pack16(Wf, wf8, i);
      else if (w == 1) pack16(Uf, uf8, i);
      else if (w == 2) pack16(Wh, wh8, i);
      else             pack16(Uh, uh8, i);
    }
  }
}

// Expand ns8 (int8) -> both int32 output halves, fully coalesced.
__global__ void expand_out(const int8_t* __restrict__ ns8,
                           int* __restrict__ out1, int* __restrict__ out2, int n16){
  const int stride = gridDim.x * blockDim.x;
  for (int i = blockIdx.x * blockDim.x + threadIdx.x; i < n16; i += stride){
    int4 pk = ((const int4*)ns8)[i];     // 16 int8 values
#pragma unroll
    for (int w = 0; w < 4; w++){
      int word = (&pk.x)[w];
      int4 o;
      o.x = (int)(int8_t)(word & 255);
      o.y = (int)(int8_t)((word >> 8) & 255);
      o.z = (int)(int8_t)((word >> 16) & 255);
      o.w = (int)(int8_t)(word >> 24);
      ((int4*)out1)[i * 4 + w] = o;
      ((int4*)out2)[i * 4 + w] = o;
    }
  }
}

// Duplicate first half of d_out into second half (int4). Fallback path only.
__global__ void dup_out(const int* __restrict__ src, int* __restrict__ dst, int n4){
  int stride = gridDim.x * blockDim.x;
  for (int i = blockIdx.x * blockDim.x + threadIdx.x; i < n4; i += stride)
    ((int4*)dst)[i] = ((const int4*)src)[i];
}

// ---- shared K-loop: EXACT R3 main loop (proven 248us/dispatch) ----
// 4 waves of 64x64, single 32KB LDS buffer, serial STAGE->sync->COMPUTE->sync,
// natural block mapping (col-fast), XOR-swizzled LDS (0 bank conflicts).
__device__ __forceinline__ void kloop_dual(
    const int8_t* __restrict__ A1, const int8_t* __restrict__ A2,
    const int8_t* __restrict__ B1, const int8_t* __restrict__ B2,
    int8_t* lds, int rowbase, int colbase,
    int tid, int lane, int wrow, int wcol,
    v4i accA[4][4], v4i accB[4][4])
{
  const int srow   = tid >> 2;   // 0..63 staging row within 64-row pass
  const int schunk = tid & 3;    // 16B chunk within 64B row
  const int chunk  = lane >> 4;  // frag-read 16B chunk
  const int rl     = lane & 15;

  for (int kk = 0; kk < NK; ++kk){
    const int k0 = kk * 64;
#pragma unroll
    for (int p = 0; p < 2; p++){
      const int row = p * 64 + srow;
      const int swc = schunk ^ ((row >> 1) & 3);       // XOR swizzle (involution)
      const size_t aoff = (size_t)(rowbase + row) * HH + k0 + swc * 16;
      const size_t boff = (size_t)(colbase + row) * HH + k0 + swc * 16;
      const int ldst = p * 4096 + tid * 16;
      __builtin_amdgcn_global_load_lds((const __attribute__((address_space(1))) void*)(A1 + aoff),
                                       (__attribute__((address_space(3))) void*)(lds + ldst), 16, 0, 0);
      __builtin_amdgcn_global_load_lds((const __attribute__((address_space(1))) void*)(A2 + aoff),
                                       (__attribute__((address_space(3))) void*)(lds + 8192 + ldst), 16, 0, 0);
      __builtin_amdgcn_global_load_lds((const __attribute__((address_space(1))) void*)(B1 + boff),
                                       (__attribute__((address_space(3))) void*)(lds + 16384 + ldst), 16, 0, 0);
      __builtin_amdgcn_global_load_lds((const __attribute__((address_space(1))) void*)(B2 + boff),
                                       (__attribute__((address_space(3))) void*)(lds + 24576 + ldst), 16, 0, 0);
    }
    __syncthreads();

    {
      v4i af[4], bf[4];
#pragma unroll
      for (int m = 0; m < 4; m++){
        const int row = wrow * 64 + m * 16 + rl;
        af[m] = *(const v4i*)(lds + row * 64 + ((chunk ^ ((row >> 1) & 3)) << 4));
      }
#pragma unroll
      for (int n = 0; n < 4; n++){
        const int row = wcol * 64 + n * 16 + rl;
        bf[n] = *(const v4i*)(lds + 16384 + row * 64 + ((chunk ^ ((row >> 1) & 3)) << 4));
      }
#pragma unroll
      for (int m = 0; m < 4; m++)
#pragma unroll
        for (int n = 0; n < 4; n++)
          accA[m][n] = __builtin_amdgcn_mfma_i32_16x16x64_i8(af[m], bf[n], accA[m][n], 0, 0, 0);
    }
    {
      v4i af[4], bf[4];
#pragma unroll
      for (int m = 0; m < 4; m++){
        const int row = wrow * 64 + m * 16 + rl;
        af[m] = *(const v4i*)(lds + 8192 + row * 64 + ((chunk ^ ((row >> 1) & 3)) << 4));
      }
#pragma unroll
      for (int n = 0; n < 4; n++){
        const int row = wcol * 64 + n * 16 + rl;
        bf[n] = *(const v4i*)(lds + 24576 + row * 64 + ((chunk ^ ((row >> 1) & 3)) << 4));
      }
#pragma unroll
      for (int m = 0; m < 4; m++)
#pragma unroll
        for (int n = 0; n < 4; n++)
          accB[m][n] = __builtin_amdgcn_mfma_i32_16x16x64_i8(af[m], bf[n], accB[m][n], 0, 0, 0);
    }
    __syncthreads();
  }
}

#define GEMM_PROLOGUE \
  __shared__ __align__(16) int8_t lds[4 * 8192]; \
  const int tid  = threadIdx.x; \
  const int lane = tid & 63; \
  const int wave = tid >> 6; \
  const int wrow = wave >> 1, wcol = wave & 1; \
  const int bid  = blockIdx.x; \
  const int rowbase = (bid >> 4) * 128; \
  const int colbase = (bid & 15) * 128; \
  v4i accA[4][4], accB[4][4]; \
  const v4i vzero = {0, 0, 0, 0}; \
  _Pragma("unroll") \
  for (int m = 0; m < 4; m++) \
    _Pragma("unroll") \
    for (int n = 0; n < 4; n++){ accA[m][n] = vzero; accB[m][n] = vzero; } \
  kloop_dual(A1, A2, B1, B2, lds, rowbase, colbase, tid, lane, wrow, wcol, accA, accB); \
  const int q = lane >> 4;

#define EPI_LOOP_BEGIN \
  _Pragma("unroll") \
  for (int m = 0; m < 4; m++){ \
    _Pragma("unroll") \
    for (int n = 0; n < 4; n++){ \
      const int gcol = colbase + wcol * 64 + n * 16 + (lane & 15); \
      const int bval = bias[gcol]; \
      _Pragma("unroll") \
      for (int r = 0; r < 4; r++){ \
        const int grow = rowbase + wrow * 64 + m * 16 + q * 4 + r; \
        const size_t idx = (size_t)grow * HH + gcol; \
        const int v1 = clip127(fdiv720(accA[m][n][r])); \
        const int v2 = clip127(fdiv720(accB[m][n][r])); \
        const int t  = clip127(v1 + v2 + bval); \
        const int st = state8[idx];

#define EPI_LOOP_END }}}

// ws path, phase 1: fg8 (u8) + gated int8
__global__ __launch_bounds__(256, 2)
void gemm_p1(const int8_t* __restrict__ A1, const int8_t* __restrict__ A2,
             const int8_t* __restrict__ B1, const int8_t* __restrict__ B2,
             const int* __restrict__ bias, const int8_t* __restrict__ state8,
             uint8_t* __restrict__ fg8, int8_t* __restrict__ g8out)
{
  GEMM_PROLOGUE
  EPI_LOOP_BEGIN
    const int fg = t + 127;                    // in [0,254]
    fg8[idx]   = (uint8_t)fg;
    g8out[idx] = (int8_t)clip127((fg * st) >> 8);
  EPI_LOOP_END
}

// ws path, phase 2: ns stored as int8 INTO fg8 (same-thread read-then-write)
__global__ __launch_bounds__(256, 2)
void gemm_p2(const int8_t* __restrict__ A1, const int8_t* __restrict__ A2,
             const int8_t* __restrict__ B1, const int8_t* __restrict__ B2,
             const int* __restrict__ bias, const int8_t* __restrict__ state8,
             uint8_t* fg8)
{
  GEMM_PROLOGUE
  EPI_LOOP_BEGIN
    const int fg = (int)fg8[idx];
    const int ns = clip127(st + ((fg * (t - st)) >> 8));
    fg8[idx] = (uint8_t)(int8_t)ns;            // becomes ns8 for expand_out
  EPI_LOOP_END
}

// fallback, phase 3: fg carried int32 in out1 + gated int8
__global__ __launch_bounds__(256, 2)
void gemm_fb3(const int8_t* __restrict__ A1, const int8_t* __restrict__ A2,
              const int8_t* __restrict__ B1, const int8_t* __restrict__ B2,
              const int* __restrict__ bias, const int8_t* __restrict__ state8,
              int* __restrict__ out1, int8_t* __restrict__ g8out)
{
  GEMM_PROLOGUE
  EPI_LOOP_BEGIN
    const int fg = t + 127;
    out1[idx]  = fg;
    g8out[idx] = (int8_t)clip127((fg * st) >> 8);
  EPI_LOOP_END
}

// fallback, phase 4: read fg from out1, write ns (same-thread r/w)
__global__ __launch_bounds__(256, 2)
void gemm_fb4(const int8_t* __restrict__ A1, const int8_t* __restrict__ A2,
              const int8_t* __restrict__ B1, const int8_t* __restrict__ B2,
              const int* __restrict__ bias, const int8_t* __restrict__ state8,
              int* out1)
{
  GEMM_PROLOGUE
  EPI_LOOP_BEGIN
    const int fg = out1[idx];
    const int ns = clip127(st + ((fg * (t - st)) >> 8));
    out1[idx] = ns;
  EPI_LOOP_END
}

extern "C" void kernel_launch(void* const* d_in, const int* in_sizes, int n_in,
                              void* d_out, int out_size, void* d_ws, size_t ws_size,
                              hipStream_t stream){
  const int* x  = (const int*)d_in[0];
  const int* st = (const int*)d_in[1];
  const int* Wf = (const int*)d_in[2];
  const int* Uf = (const int*)d_in[3];
  const int* bf = (const int*)d_in[4];
  const int* Wh = (const int*)d_in[5];
  const int* Uh = (const int*)d_in[6];
  const int* bh = (const int*)d_in[7];

  const size_t NBH = (size_t)BB * HH;   // 33,554,432 elements
  const size_t NW  = (size_t)HH * HH;   //  4,194,304 elements
  const size_t need = 4 * NBH + 4 * NW; // 144 MiB int8 scratch (same as R10)

  int* out1 = (int*)d_out;

  if (ws_size >= need){
    // ws path: x8 | s8 | g8 | fg8(->ns8) | 4 weights in d_ws.
    int8_t*  x8  = (int8_t*)d_ws;
    int8_t*  s8  = x8 + NBH;
    int8_t*  g8  = s8 + NBH;
    uint8_t* fg8 = (uint8_t*)(g8 + NBH);
    int8_t*  wf8 = (int8_t*)fg8 + NBH;
    int8_t*  uf8 = wf8 + NW;
    int8_t*  wh8 = uf8 + NW;
    int8_t*  uh8 = wh8 + NW;
    pack_all<<<2048, 256, 0, stream>>>(x, st, Wf, Uf, Wh, Uh,
                                       x8, s8, wf8, uf8, wh8, uh8);
    gemm_p1<<<2048, 256, 0, stream>>>(x8, s8, wf8, uf8, bf, s8, fg8, g8);
    gemm_p2<<<2048, 256, 0, stream>>>(x8, g8, wh8, uh8, bh, s8, fg8);
    expand_out<<<2048, 256, 0, stream>>>((const int8_t*)fg8, out1, out1 + NBH,
                                         (int)(NBH / 16));
  } else {
    // Fallback (R3-equivalent, known-correct): scratch in d_out second half,
    // fg carried as int32 in out1, dup at the end.
    int8_t* base = (int8_t*)d_out + NBH * 4;
    int8_t* x8  = base;
    int8_t* s8  = x8 + NBH;
    int8_t* g8  = s8 + NBH;
    int8_t* wf8 = g8 + NBH;
    int8_t* uf8 = wf8 + NW;
    int8_t* wh8 = uf8 + NW;
    int8_t* uh8 = wh8 + NW;
    pack_all<<<2048, 256, 0, stream>>>(x, st, Wf, Uf, Wh, Uh,
                                       x8, s8, wf8, uf8, wh8, uh8);
    gemm_fb3<<<2048, 256, 0, stream>>>(x8, s8, wf8, uf8, bf, s8, out1, g8);
    gemm_fb4<<<2048, 256, 0, stream>>>(x8, g8, wh8, uh8, bh, s8, out1);
    dup_out<<<2048, 256, 0, stream>>>(out1, out1 + NBH, (int)(NBH / 4));
  }
}